// Round 1
// baseline (363.536 us; speedup 1.0000x reference)
//
#include <hip/hip_runtime.h>
#include <hip/hip_bf16.h>

// ---------------------------------------------------------------------------
// CrossAttentionBlock: bilinear 3x upsample -> QKV 1x1 projections ->
// full cross-attention (N=9216, E=64, Co=32) -> 1x1 conv + BN + ReLU.
// Flash-style (no NxN score matrix). fp16 MFMA 16x16x32, fp32 accumulate.
// Softmax without max subtraction (scores bounded ~|0.5|), so split-m
// partials combine additively.
// ---------------------------------------------------------------------------

constexpr int B   = 2;
constexpr int N   = 9216;   // 96*96
constexpr int E   = 64;
constexpr int CO  = 32;
constexpr int CT  = 64;
constexpr int SPLIT  = 8;          // m-chunks per row-tile
constexpr int MCHUNK = N / SPLIT;  // 1152

typedef _Float16 f16x8 __attribute__((ext_vector_type(8)));
typedef float    f32x4 __attribute__((ext_vector_type(4)));

#define MFMA(a, b, c) __builtin_amdgcn_mfma_f32_16x16x32_f16((a), (b), (c), 0, 0, 0)

union H2 { _Float16 h[2]; unsigned u; };

// exp2 scale: exp(s/8) == exp2(s * 0.125 * log2(e))
#define SC 0.18033688011112042f

// ---------------------------------------------------------------------------
// Kernel 1: bilinear upsample (half-pixel, clamped) + Q projection.
// Q stored [B][N][E] fp16. One thread per output pixel.
// ---------------------------------------------------------------------------
__global__ __launch_bounds__(256) void proj_q_kernel(
    const float* __restrict__ xt,   // [B][64][32][32]
    const float* __restrict__ qw,   // [64][64]
    const float* __restrict__ qb,   // [64]
    _Float16* __restrict__ Q)
{
  const int p  = blockIdx.x * 256 + threadIdx.x;   // 0..18431
  const int b  = p / N, n = p % N;
  const int ho = n / 96, wo = n % 96;

  const float sh = (ho + 0.5f) * (1.0f / 3.0f) - 0.5f;
  const float sw = (wo + 0.5f) * (1.0f / 3.0f) - 0.5f;
  int h0 = (int)floorf(sh); const float fh = sh - (float)h0;
  int w0 = (int)floorf(sw); const float fw = sw - (float)w0;
  int h1 = min(h0 + 1, 31); h0 = max(h0, 0);
  int w1 = min(w0 + 1, 31); w0 = max(w0, 0);

  const float c00 = (1.f - fh) * (1.f - fw), c01 = (1.f - fh) * fw;
  const float c10 = fh * (1.f - fw),         c11 = fh * fw;
  const int i00 = h0 * 32 + w0, i01 = h0 * 32 + w1;
  const int i10 = h1 * 32 + w0, i11 = h1 * 32 + w1;

  const float* xb = xt + (size_t)b * 64 * 1024;
  float xup[64];
#pragma unroll
  for (int c = 0; c < 64; ++c) {
    const float* xc = xb + (size_t)c * 1024;
    xup[c] = xc[i00] * c00 + xc[i01] * c01 + xc[i10] * c10 + xc[i11] * c11;
  }

  _Float16* Qp = Q + (size_t)p * E;
  for (int e0 = 0; e0 < 64; e0 += 8) {
    union { _Float16 h[8]; uint4 v; } pk;
#pragma unroll
    for (int j = 0; j < 8; ++j) {
      const int e = e0 + j;
      float acc = qb[e];
#pragma unroll
      for (int c = 0; c < 64; ++c) acc += xup[c] * qw[e * 64 + c];
      pk.h[j] = (_Float16)acc;
    }
    *(uint4*)(Qp + e0) = pk.v;
  }
}

// ---------------------------------------------------------------------------
// Kernel 2: K and V projections from x_optical.
// K stored [B][N][E] fp16; V stored transposed [B][CO][N] fp16.
// ---------------------------------------------------------------------------
__global__ __launch_bounds__(256) void proj_kv_kernel(
    const float* __restrict__ xo,   // [B][32][N]
    const float* __restrict__ kw, const float* __restrict__ kb,
    const float* __restrict__ vw, const float* __restrict__ vb,
    _Float16* __restrict__ K, _Float16* __restrict__ Vt)
{
  const int p = blockIdx.x * 256 + threadIdx.x;
  const int b = p / N, n = p % N;

  const float* xb = xo + (size_t)b * CO * N + n;
  float x[32];
#pragma unroll
  for (int c = 0; c < 32; ++c) x[c] = xb[(size_t)c * N];

  _Float16* Kp = K + (size_t)p * E;
  for (int e0 = 0; e0 < 64; e0 += 8) {
    union { _Float16 h[8]; uint4 v; } pk;
#pragma unroll
    for (int j = 0; j < 8; ++j) {
      const int e = e0 + j;
      float acc = kb[e];
#pragma unroll
      for (int c = 0; c < 32; ++c) acc += x[c] * kw[e * 32 + c];
      pk.h[j] = (_Float16)acc;
    }
    *(uint4*)(Kp + e0) = pk.v;
  }

  _Float16* Vp = Vt + (size_t)b * CO * N + n;
#pragma unroll
  for (int o = 0; o < 32; ++o) {
    float acc = vb[o];
#pragma unroll
    for (int c = 0; c < 32; ++c) acc += x[c] * vw[o * 32 + c];
    Vp[(size_t)o * N] = (_Float16)acc;
  }
}

// ---------------------------------------------------------------------------
// Kernel 3: flash attention partials.
// Each wave: 32 Q-rows (two 16-row tiles), one m-chunk of 1152.
// Swapped QK^T: S^T = mfma(A=K-frag, B=Q-frag); lane holds S^T[m=4g+r][n=l&15].
// P^T B-fragment for PV assembled via 8 ds_bpermute per 32-m step.
// Unnormalized accumulation; partials to f32 workspace.
// ---------------------------------------------------------------------------
__global__ __launch_bounds__(256) void attn_kernel(
    const _Float16* __restrict__ Q,
    const _Float16* __restrict__ K,
    const _Float16* __restrict__ Vt,
    float* __restrict__ OutWS,   // [SPLIT][B][N][CO]
    float* __restrict__ SumWS)   // [SPLIT][B][N]
{
  const int tid  = threadIdx.x;
  const int wave = tid >> 6, lane = tid & 63;
  const int r16  = lane & 15, g = lane >> 4;

  const int work  = blockIdx.x;
  const int chunk = work & (SPLIT - 1);
  const int t128  = work >> 3;            // 0..143
  const int b     = t128 / 72;
  const int rowbase = (t128 % 72) * 128 + wave * 32;

  const _Float16* Qb = Q  + ((size_t)b * N + rowbase) * E;
  const _Float16* Kb = K  + (size_t)b * N * E;
  const _Float16* Vb = Vt + (size_t)b * CO * N;

  // Q B-fragments: 2 row-tiles x 2 k-steps (contiguous 16B per lane)
  f16x8 qf[2][2];
#pragma unroll
  for (int rt = 0; rt < 2; ++rt)
#pragma unroll
    for (int ks = 0; ks < 2; ++ks)
      qf[rt][ks] = *(const f16x8*)(Qb + (rt * 16 + r16) * E + ks * 32 + g * 8);

  f32x4 oacc[2][2];
#pragma unroll
  for (int a = 0; a < 2; ++a)
#pragma unroll
    for (int c = 0; c < 2; ++c) oacc[a][c] = (f32x4){0.f, 0.f, 0.f, 0.f};
  float sume[2] = {0.f, 0.f};

  // shfl sources for P^T fragment exchange
  const int srcLo = r16 + 32 * (g & 1);
  const int srcHi = srcLo + 16;
  const bool selLo = (g < 2);

  const int mstart = chunk * MCHUNK;
  for (int m = mstart; m < mstart + MCHUNK; m += 32) {
    f16x8 kf[2][2];
#pragma unroll
    for (int mt = 0; mt < 2; ++mt)
#pragma unroll
      for (int ks = 0; ks < 2; ++ks)
        kf[mt][ks] = *(const f16x8*)(Kb + (size_t)(m + mt * 16 + r16) * E + ks * 32 + g * 8);
    f16x8 vf[2];
#pragma unroll
    for (int ot = 0; ot < 2; ++ot)
      vf[ot] = *(const f16x8*)(Vb + (size_t)(ot * 16 + r16) * N + m + g * 8);

#pragma unroll
    for (int rt = 0; rt < 2; ++rt) {
      // S^T tiles: rows m_local (tile0: 0-15, tile1: 16-31), cols n
      f32x4 s0 = (f32x4){0.f, 0.f, 0.f, 0.f};
      f32x4 s1 = (f32x4){0.f, 0.f, 0.f, 0.f};
      s0 = MFMA(kf[0][0], qf[rt][0], s0);
      s0 = MFMA(kf[0][1], qf[rt][1], s0);
      s1 = MFMA(kf[1][0], qf[rt][0], s1);
      s1 = MFMA(kf[1][1], qf[rt][1], s1);

      float p[2][4];
#pragma unroll
      for (int i = 0; i < 4; ++i) {
        p[0][i] = __builtin_amdgcn_exp2f(s0[i] * SC);
        p[1][i] = __builtin_amdgcn_exp2f(s1[i] * SC);
      }
      sume[rt] += p[0][0] + p[0][1] + p[0][2] + p[0][3]
                + p[1][0] + p[1][1] + p[1][2] + p[1][3];

      // pack pairs (m, m+1) -> u32 of 2 fp16
      unsigned pk[2][2];
#pragma unroll
      for (int t = 0; t < 2; ++t) {
        H2 a; a.h[0] = (_Float16)p[t][0]; a.h[1] = (_Float16)p[t][1]; pk[t][0] = a.u;
        H2 c; c.h[0] = (_Float16)p[t][2]; c.h[1] = (_Float16)p[t][3]; pk[t][1] = c.u;
      }
      // B-frag word w holds P(n=l&15, m=8g+2w, 8g+2w+1):
      //   src lane = (l&15)+16*(2*(g&1)+(w>>1)); tile select by g>>1
      const unsigned w0a = __shfl(pk[0][0], srcLo), w0b = __shfl(pk[1][0], srcLo);
      const unsigned w1a = __shfl(pk[0][1], srcLo), w1b = __shfl(pk[1][1], srcLo);
      const unsigned w2a = __shfl(pk[0][0], srcHi), w2b = __shfl(pk[1][0], srcHi);
      const unsigned w3a = __shfl(pk[0][1], srcHi), w3b = __shfl(pk[1][1], srcHi);
      union { unsigned u[4]; f16x8 v; } pb;
      pb.u[0] = selLo ? w0a : w0b;
      pb.u[1] = selLo ? w1a : w1b;
      pb.u[2] = selLo ? w2a : w2b;
      pb.u[3] = selLo ? w3a : w3b;

      // out^T[o][n] += Vt-frag * P^T-frag
      oacc[rt][0] = MFMA(vf[0], pb.v, oacc[rt][0]);
      oacc[rt][1] = MFMA(vf[1], pb.v, oacc[rt][1]);
    }
  }

  // reduce sumexp across the four 16-lane groups (each held different m)
#pragma unroll
  for (int rt = 0; rt < 2; ++rt) {
    sume[rt] += __shfl_xor(sume[rt], 16);
    sume[rt] += __shfl_xor(sume[rt], 32);
  }

  float* OW = OutWS + (size_t)(chunk * B + b) * N * CO;
  float* SW = SumWS + (size_t)(chunk * B + b) * N;
#pragma unroll
  for (int rt = 0; rt < 2; ++rt) {
    const int n = rowbase + rt * 16 + r16;
    if (g == 0) SW[n] = sume[rt];
#pragma unroll
    for (int ot = 0; ot < 2; ++ot)
#pragma unroll
      for (int i = 0; i < 4; ++i)
        OW[(size_t)n * CO + ot * 16 + 4 * g + i] = oacc[rt][ot][i];
  }
}

// ---------------------------------------------------------------------------
// Kernel 4: combine split-m partials, normalize, out_w conv, BN, ReLU.
// Block: 64 pixels x 4 t-groups; wave-uniform t -> broadcast weight reads,
// lane-consecutive n -> coalesced stores.
// ---------------------------------------------------------------------------
__global__ __launch_bounds__(256) void epi_kernel(
    const float* __restrict__ OutWS, const float* __restrict__ SumWS,
    const float* __restrict__ ow, const float* __restrict__ gamma,
    const float* __restrict__ beta, const float* __restrict__ mean,
    const float* __restrict__ var, float* __restrict__ out)
{
  const int tid  = threadIdx.x;
  const int nloc = tid & 63, tg = tid >> 6;
  const int pix  = blockIdx.x * 64 + nloc;
  const int b    = pix / N, n = pix % N;

  float s = 0.f;
#pragma unroll
  for (int sc = 0; sc < SPLIT; ++sc) s += SumWS[(size_t)(sc * B + b) * N + n];
  const float inv = 1.f / s;

  float onr[CO];
#pragma unroll
  for (int o = 0; o < CO; ++o) {
    float a = 0.f;
#pragma unroll
    for (int sc = 0; sc < SPLIT; ++sc)
      a += OutWS[((size_t)(sc * B + b) * N + n) * CO + o];
    onr[o] = a * inv;
  }

#pragma unroll
  for (int i = 0; i < 16; ++i) {
    const int t = tg + 4 * i;
    float acc = 0.f;
#pragma unroll
    for (int o = 0; o < CO; ++o) acc += onr[o] * ow[t * CO + o];
    const float scl = gamma[t] * rsqrtf(var[t] + 1e-5f);
    const float bia = beta[t] - mean[t] * scl;
    const float gv  = acc * scl + bia;
    out[(size_t)(b * CT + t) * N + n] = fmaxf(gv, 0.f);
  }
}

// ---------------------------------------------------------------------------
extern "C" void kernel_launch(void* const* d_in, const int* in_sizes, int n_in,
                              void* d_out, int out_size, void* d_ws, size_t ws_size,
                              hipStream_t stream) {
  const float* xt = (const float*)d_in[0];
  const float* xo = (const float*)d_in[1];
  const float* qw = (const float*)d_in[2];
  const float* qb = (const float*)d_in[3];
  const float* kw = (const float*)d_in[4];
  const float* kb = (const float*)d_in[5];
  const float* vw = (const float*)d_in[6];
  const float* vb = (const float*)d_in[7];
  const float* ow = (const float*)d_in[8];
  const float* gm = (const float*)d_in[9];
  const float* bt = (const float*)d_in[10];
  const float* mn = (const float*)d_in[11];
  const float* vr = (const float*)d_in[12];

  char* ws = (char*)d_ws;
  _Float16* Qd  = (_Float16*)ws;  ws += (size_t)B * N * E * 2;        // 2.36 MB
  _Float16* Kd  = (_Float16*)ws;  ws += (size_t)B * N * E * 2;        // 2.36 MB
  _Float16* Vtd = (_Float16*)ws;  ws += (size_t)B * CO * N * 2;       // 1.18 MB
  float* OutWS  = (float*)ws;     ws += (size_t)SPLIT * B * N * CO * 4; // 18.9 MB
  float* SumWS  = (float*)ws;                                          // 0.6 MB

  proj_q_kernel<<<(B * N) / 256, 256, 0, stream>>>(xt, qw, qb, Qd);
  proj_kv_kernel<<<(B * N) / 256, 256, 0, stream>>>(xo, kw, kb, vw, vb, Kd, Vtd);
  attn_kernel<<<(N / 128) * B * SPLIT, 256, 0, stream>>>(Qd, Kd, Vtd, OutWS, SumWS);
  epi_kernel<<<(B * N) / 64, 256, 0, stream>>>(OutWS, SumWS, ow, gm, bt, mn, vr,
                                               (float*)d_out);
}